// Round 5
// baseline (164.075 us; speedup 1.0000x reference)
//
#include <hip/hip_runtime.h>

// Compact Bilinear Pooling via count-sketch algebra (no FFT):
//   out[b,d] = sum_{c1,c2 : (h1[c1]+h2[c2]) & 8191 == d} s1[c1]*s2[c2]*G[b,c1,c2]
//   G[b,c1,c2] = sum_{p<196} bottom1[b,c1,p] * bottom2[b,c2,p]
// R5: R3's LDS-staged MFMA structure, re-gridded for latency hiding:
//   - 1024 blocks (t1 split to 8x64-row tiles): 3 blocks/CU resident
//     (49.7 KB LDS each), 12 waves/CU vs R3/R4's 8.
//   - XCD swizzle: flat id = m*32+b -> id%8 = b%8, all 32 blocks of a batch
//     share an XCD -> each batch's tiles fetched ~once (FETCH 50->~33 MB).
//   - total LDS-atomic count unchanged (8.4M); flush doubles to 32 MB (cheap).

#define D     8192
#define DMASK 8191
#define C     512
#define HW    196     // 14*14, contiguous innermost
#define NB    32
#define LDK   40      // bf16/row: 32 data + 8 pad; 80B stride -> conflict-free frags
#define NCH   7       // ceil(196/32), tail zero-padded
#define NSL   32      // partial slices per batch (8 t1 x 4 t2)

typedef __attribute__((ext_vector_type(8))) short bf16x8;
typedef __attribute__((ext_vector_type(4))) float f32x4;

// fp32 -> bf16 RNE with sign-mask fold (s = +-1 -> exact xor of sign bit)
__device__ __forceinline__ unsigned short f2bf(float f, unsigned xm) {
    unsigned u = __float_as_uint(f) ^ xm;
    return (unsigned short)((u + 0x7fffu + ((u >> 16) & 1u)) >> 16);
}

// ---------------------------------------------------------------------------
// Phase 1: recover (h[c], s[c]) branch-free. Row has exactly one +-1:
//   s = sum(row);  h = s * sum(row[d]*d)   (both exact).
// ---------------------------------------------------------------------------
__global__ __launch_bounds__(256) void extract2(
    const float* __restrict__ S1, const float* __restrict__ S2,
    int* __restrict__ h1, float* __restrict__ s1,
    int* __restrict__ h2, float* __restrict__ s2)
{
    const int  row   = blockIdx.x & 511;
    const bool first = blockIdx.x < 512;
    const float* S = first ? S1 : S2;
    const float4* rp = (const float4*)(S + (size_t)row * D);
    const int tid = threadIdx.x;

    float4 v[8];
    #pragma unroll
    for (int ii = 0; ii < 8; ++ii) v[ii] = rp[tid + 256 * ii];

    float ssum = 0.f, wsum = 0.f;
    #pragma unroll
    for (int ii = 0; ii < 8; ++ii) {
        const float base = (float)(4 * (tid + 256 * ii));
        ssum += (v[ii].x + v[ii].y) + (v[ii].z + v[ii].w);
        wsum += v[ii].x * base + v[ii].y * (base + 1.f)
              + v[ii].z * (base + 2.f) + v[ii].w * (base + 3.f);
    }
    #pragma unroll
    for (int off = 32; off; off >>= 1) {
        ssum += __shfl_down(ssum, off, 64);
        wsum += __shfl_down(wsum, off, 64);
    }
    __shared__ float rs[4], rw[4];
    if ((tid & 63) == 0) { rs[tid >> 6] = ssum; rw[tid >> 6] = wsum; }
    __syncthreads();
    if (tid == 0) {
        const float st = (rs[0] + rs[1]) + (rs[2] + rs[3]);
        const float wt = (rw[0] + rw[1]) + (rw[2] + rw[3]);
        if (first) { h1[row] = (int)(wt * st); s1[row] = st; }
        else       { h2[row] = (int)(wt * st); s2[row] = st; }
    }
}

// ---------------------------------------------------------------------------
// Phase 2: bf16-MFMA GEMM (64x128 tile, K=196 padded) + LDS-histogram
// scatter + plain-store flush to partials P[b*32 + m][8192].
// 1024 blocks flat: b = id&31, m = id>>5, t1 = m>>2 (64-row), t2 = m&3 (128-row).
// 4 waves; wave w owns 32x64 quadrant: acc 2x4 tiles of 16x16.
// ---------------------------------------------------------------------------
__global__ __launch_bounds__(256, 3) void cbp_mfma(
    const float* __restrict__ b1, const float* __restrict__ b2,
    const int* __restrict__ h1, const float* __restrict__ s1,
    const int* __restrict__ h2, const float* __restrict__ s2,
    float* __restrict__ P)
{
    const int id = blockIdx.x;
    const int b  = id & 31;        // id%8 = b%8 -> batch-per-XCD locality
    const int m  = id >> 5;        // 0..31
    const int t1 = m >> 2;         // 0..7, A rows t1*64
    const int t2 = m & 3;          // 0..3, B rows t2*128

    __shared__ float hist[D];                               // 32 KB
    __shared__ __align__(16) unsigned short As[64 * LDK];   // 5 KB
    __shared__ __align__(16) unsigned short Bs[128 * LDK];  // 10 KB
    __shared__ int h1t[64], h2t[128];

    const int tid = threadIdx.x;

    // zero histogram (2048 float4)
    #pragma unroll
    for (int i = 0; i < 8; ++i) {
        float4 z = {0.f, 0.f, 0.f, 0.f};
        ((float4*)hist)[tid + 256 * i] = z;
    }
    if (tid < 64)  h1t[tid] = h1[t1 * 64 + tid];
    if (tid < 128) h2t[tid] = h2[t2 * 128 + tid];

    // staging mapping:
    //   A: 64 rows x 32 cols -> thread: row ra = tid>>2, cols ka..ka+7 (2 float4)
    //   B: 128 rows x 32 cols -> thread: row rb = tid>>1, cols kb..kb+15 (4 float4)
    const int ra = tid >> 2;
    const int ka = (tid & 3) * 8;
    const int rb = tid >> 1;
    const int kb = (tid & 1) * 16;

    const float* Abase = b1 + ((size_t)b * C + t1 * 64 + ra) * HW;
    const float* Bbase = b2 + ((size_t)b * C + t2 * 128 + rb) * HW;

    const unsigned am = (s1[t1 * 64  + ra] < 0.f) ? 0x80000000u : 0u;
    const unsigned bm = (s2[t2 * 128 + rb] < 0.f) ? 0x80000000u : 0u;

    // prefetch chunk 0 (k 0..31 always in range)
    float4 pva[2], pvb[4];
    pva[0] = *(const float4*)(Abase + ka);
    pva[1] = *(const float4*)(Abase + ka + 4);
    #pragma unroll
    for (int t = 0; t < 4; ++t)
        pvb[t] = *(const float4*)(Bbase + kb + 4 * t);

    // MFMA lane geometry: wave w -> 32x64 quadrant
    const int lane  = tid & 63;
    const int w     = tid >> 6;
    const int ln15  = lane & 15;
    const int qd    = lane >> 4;
    const int koff  = qd * 8;
    const int mbase = (w >> 1) * 32;   // 0 / 32
    const int nbase = (w & 1) * 64;    // 0 / 64

    f32x4 acc[2][4] = {};

    for (int ch = 0; ch < NCH; ++ch) {
        // staged registers -> LDS (bf16, sign folded)
        {
            uint2 u0, u1;
            u0.x = (unsigned)f2bf(pva[0].x, am) | ((unsigned)f2bf(pva[0].y, am) << 16);
            u0.y = (unsigned)f2bf(pva[0].z, am) | ((unsigned)f2bf(pva[0].w, am) << 16);
            u1.x = (unsigned)f2bf(pva[1].x, am) | ((unsigned)f2bf(pva[1].y, am) << 16);
            u1.y = (unsigned)f2bf(pva[1].z, am) | ((unsigned)f2bf(pva[1].w, am) << 16);
            *(uint2*)&As[ra * LDK + ka]     = u0;
            *(uint2*)&As[ra * LDK + ka + 4] = u1;
            #pragma unroll
            for (int t = 0; t < 2; ++t) {
                uint2 ub;
                ub.x = (unsigned)f2bf(pvb[2*t].x, bm) | ((unsigned)f2bf(pvb[2*t].y, bm) << 16);
                ub.y = (unsigned)f2bf(pvb[2*t].z, bm) | ((unsigned)f2bf(pvb[2*t].w, bm) << 16);
                *(uint2*)&Bs[rb * LDK + kb + 8 * t] = ub;
                uint2 uc;
                uc.x = (unsigned)f2bf(pvb[2*t+1].x, bm) | ((unsigned)f2bf(pvb[2*t+1].y, bm) << 16);
                uc.y = (unsigned)f2bf(pvb[2*t+1].z, bm) | ((unsigned)f2bf(pvb[2*t+1].w, bm) << 16);
                *(uint2*)&Bs[rb * LDK + kb + 8 * t + 4] = uc;
            }
        }
        __syncthreads();

        // issue next chunk's global loads (stay in flight across MFMAs)
        if (ch + 1 < NCH) {
            const int gk = (ch + 1) * 32;
            const float4 z = {0.f, 0.f, 0.f, 0.f};
            const int gka = gk + ka;
            pva[0] = (gka + 4 <= HW) ? *(const float4*)(Abase + gka)     : z;
            pva[1] = (gka + 8 <= HW) ? *(const float4*)(Abase + gka + 4) : z;
            #pragma unroll
            for (int t = 0; t < 4; ++t) {
                const int gkb = gk + kb + 4 * t;
                pvb[t] = (gkb + 4 <= HW) ? *(const float4*)(Bbase + gkb) : z;
            }
        }

        // fragment reads (conflict-free 80B stride) + 8 MFMAs
        bf16x8 av[2], bv[4];
        #pragma unroll
        for (int i = 0; i < 2; ++i)
            av[i] = *(const bf16x8*)&As[(mbase + i * 16 + ln15) * LDK + koff];
        #pragma unroll
        for (int j = 0; j < 4; ++j)
            bv[j] = *(const bf16x8*)&Bs[(nbase + j * 16 + ln15) * LDK + koff];
        #pragma unroll
        for (int i = 0; i < 2; ++i)
            #pragma unroll
            for (int j = 0; j < 4; ++j)
                acc[i][j] = __builtin_amdgcn_mfma_f32_16x16x32_bf16(
                    av[i], bv[j], acc[i][j], 0, 0, 0);
        __syncthreads();
    }

    // scatter: C/D layout col=lane&15, row=(lane>>4)*4+reg  [m89/m91]
    int p2v[4];
    #pragma unroll
    for (int j = 0; j < 4; ++j)
        p2v[j] = h2t[nbase + j * 16 + ln15];

    #pragma unroll
    for (int i = 0; i < 2; ++i)
        #pragma unroll
        for (int qq = 0; qq < 4; ++qq) {
            const int p1 = h1t[mbase + i * 16 + qd * 4 + qq];
            #pragma unroll
            for (int j = 0; j < 4; ++j)
                atomicAdd(&hist[(p1 + p2v[j]) & DMASK], acc[i][j][qq]);
        }

    __syncthreads();

    // flush: plain coalesced float4 stores to this block's partial slice
    float* Pslice = P + (size_t)(b * NSL + m) * D;
    #pragma unroll
    for (int i = 0; i < 8; ++i)
        ((float4*)Pslice)[tid + 256 * i] = ((const float4*)hist)[tid + 256 * i];
}

// ---------------------------------------------------------------------------
// Phase 3: out[b,d] = sum of 32 slices. 256 blocks x 256 threads.
// ---------------------------------------------------------------------------
__global__ __launch_bounds__(256) void reduce32(
    const float* __restrict__ P, float* __restrict__ out)
{
    const int idx4 = blockIdx.x * 256 + threadIdx.x;   // 0..65535
    const int b    = idx4 >> 11;
    const int d4   = idx4 & 2047;

    const float4* base = (const float4*)(P + (size_t)b * NSL * D) + d4;
    float4 acc = base[0];
    #pragma unroll
    for (int s = 1; s < NSL; ++s) {
        float4 v = base[s * (D / 4)];
        acc.x += v.x; acc.y += v.y; acc.z += v.z; acc.w += v.w;
    }
    ((float4*)out)[idx4] = acc;
}

// ---------------------------------------------------------------------------
extern "C" void kernel_launch(void* const* d_in, const int* in_sizes, int n_in,
                              void* d_out, int out_size, void* d_ws, size_t ws_size,
                              hipStream_t stream)
{
    const float* bottom1 = (const float*)d_in[0];
    const float* bottom2 = (const float*)d_in[1];
    const float* S1      = (const float*)d_in[2];
    const float* S2      = (const float*)d_in[3];
    float* out = (float*)d_out;

    float* P  = (float*)d_ws;                 // 1024 * 8192 floats = 32 MB
    int*   h1 = (int*)(P + (size_t)NB * NSL * D);
    int*   h2 = h1 + C;
    float* s1 = (float*)(h2 + C);
    float* s2 = s1 + C;

    extract2<<<1024, 256, 0, stream>>>(S1, S2, h1, s1, h2, s2);
    cbp_mfma<<<1024, 256, 0, stream>>>(bottom1, bottom2,
                                       h1, s1, h2, s2, P);
    reduce32<<<256, 256, 0, stream>>>(P, out);
}

// Round 6
// 160.890 us; speedup vs baseline: 1.0198x; 1.0198x over previous
//
#include <hip/hip_runtime.h>

// Compact Bilinear Pooling via count-sketch algebra (no FFT):
//   out[b,d] = sum_{c1,c2 : (h1[c1]+h2[c2]) & 8191 == d} s1[c1]*s2[c2]*G[b,c1,c2]
//   G[b,c1,c2] = sum_{p<196} bottom1[b,c1,p] * bottom2[b,c2,p]
// R6: identical to R5 except ONE change: hist scatter uses unsafeAtomicAdd
// (hardware ds_add_f32) instead of atomicAdd (which may lower to a CAS retry
// loop under safe-FP-atomics -- suspected source of the invariant ~70us).

#define D     8192
#define DMASK 8191
#define C     512
#define HW    196     // 14*14, contiguous innermost
#define NB    32
#define LDK   40      // bf16/row: 32 data + 8 pad; 80B stride -> conflict-free frags
#define NCH   7       // ceil(196/32), tail zero-padded
#define NSL   32      // partial slices per batch (8 t1 x 4 t2)

typedef __attribute__((ext_vector_type(8))) short bf16x8;
typedef __attribute__((ext_vector_type(4))) float f32x4;

// fp32 -> bf16 RNE with sign-mask fold (s = +-1 -> exact xor of sign bit)
__device__ __forceinline__ unsigned short f2bf(float f, unsigned xm) {
    unsigned u = __float_as_uint(f) ^ xm;
    return (unsigned short)((u + 0x7fffu + ((u >> 16) & 1u)) >> 16);
}

// ---------------------------------------------------------------------------
// Phase 1: recover (h[c], s[c]) branch-free. Row has exactly one +-1:
//   s = sum(row);  h = s * sum(row[d]*d)   (both exact).
// ---------------------------------------------------------------------------
__global__ __launch_bounds__(256) void extract2(
    const float* __restrict__ S1, const float* __restrict__ S2,
    int* __restrict__ h1, float* __restrict__ s1,
    int* __restrict__ h2, float* __restrict__ s2)
{
    const int  row   = blockIdx.x & 511;
    const bool first = blockIdx.x < 512;
    const float* S = first ? S1 : S2;
    const float4* rp = (const float4*)(S + (size_t)row * D);
    const int tid = threadIdx.x;

    float4 v[8];
    #pragma unroll
    for (int ii = 0; ii < 8; ++ii) v[ii] = rp[tid + 256 * ii];

    float ssum = 0.f, wsum = 0.f;
    #pragma unroll
    for (int ii = 0; ii < 8; ++ii) {
        const float base = (float)(4 * (tid + 256 * ii));
        ssum += (v[ii].x + v[ii].y) + (v[ii].z + v[ii].w);
        wsum += v[ii].x * base + v[ii].y * (base + 1.f)
              + v[ii].z * (base + 2.f) + v[ii].w * (base + 3.f);
    }
    #pragma unroll
    for (int off = 32; off; off >>= 1) {
        ssum += __shfl_down(ssum, off, 64);
        wsum += __shfl_down(wsum, off, 64);
    }
    __shared__ float rs[4], rw[4];
    if ((tid & 63) == 0) { rs[tid >> 6] = ssum; rw[tid >> 6] = wsum; }
    __syncthreads();
    if (tid == 0) {
        const float st = (rs[0] + rs[1]) + (rs[2] + rs[3]);
        const float wt = (rw[0] + rw[1]) + (rw[2] + rw[3]);
        if (first) { h1[row] = (int)(wt * st); s1[row] = st; }
        else       { h2[row] = (int)(wt * st); s2[row] = st; }
    }
}

// ---------------------------------------------------------------------------
// Phase 2: bf16-MFMA GEMM (64x128 tile, K=196 padded) + LDS-histogram
// scatter (ds_add_f32 via unsafeAtomicAdd) + plain-store flush to partials.
// 1024 blocks flat: b = id&31 (XCD locality), m = id>>5, t1 = m>>2, t2 = m&3.
// ---------------------------------------------------------------------------
__global__ __launch_bounds__(256, 3) void cbp_mfma(
    const float* __restrict__ b1, const float* __restrict__ b2,
    const int* __restrict__ h1, const float* __restrict__ s1,
    const int* __restrict__ h2, const float* __restrict__ s2,
    float* __restrict__ P)
{
    const int id = blockIdx.x;
    const int b  = id & 31;
    const int m  = id >> 5;
    const int t1 = m >> 2;
    const int t2 = m & 3;

    __shared__ float hist[D];                               // 32 KB
    __shared__ __align__(16) unsigned short As[64 * LDK];   // 5 KB
    __shared__ __align__(16) unsigned short Bs[128 * LDK];  // 10 KB
    __shared__ int h1t[64], h2t[128];

    const int tid = threadIdx.x;

    #pragma unroll
    for (int i = 0; i < 8; ++i) {
        float4 z = {0.f, 0.f, 0.f, 0.f};
        ((float4*)hist)[tid + 256 * i] = z;
    }
    if (tid < 64)  h1t[tid] = h1[t1 * 64 + tid];
    if (tid < 128) h2t[tid] = h2[t2 * 128 + tid];

    const int ra = tid >> 2;
    const int ka = (tid & 3) * 8;
    const int rb = tid >> 1;
    const int kb = (tid & 1) * 16;

    const float* Abase = b1 + ((size_t)b * C + t1 * 64 + ra) * HW;
    const float* Bbase = b2 + ((size_t)b * C + t2 * 128 + rb) * HW;

    const unsigned am = (s1[t1 * 64  + ra] < 0.f) ? 0x80000000u : 0u;
    const unsigned bm = (s2[t2 * 128 + rb] < 0.f) ? 0x80000000u : 0u;

    float4 pva[2], pvb[4];
    pva[0] = *(const float4*)(Abase + ka);
    pva[1] = *(const float4*)(Abase + ka + 4);
    #pragma unroll
    for (int t = 0; t < 4; ++t)
        pvb[t] = *(const float4*)(Bbase + kb + 4 * t);

    const int lane  = tid & 63;
    const int w     = tid >> 6;
    const int ln15  = lane & 15;
    const int qd    = lane >> 4;
    const int koff  = qd * 8;
    const int mbase = (w >> 1) * 32;
    const int nbase = (w & 1) * 64;

    f32x4 acc[2][4] = {};

    for (int ch = 0; ch < NCH; ++ch) {
        {
            uint2 u0, u1;
            u0.x = (unsigned)f2bf(pva[0].x, am) | ((unsigned)f2bf(pva[0].y, am) << 16);
            u0.y = (unsigned)f2bf(pva[0].z, am) | ((unsigned)f2bf(pva[0].w, am) << 16);
            u1.x = (unsigned)f2bf(pva[1].x, am) | ((unsigned)f2bf(pva[1].y, am) << 16);
            u1.y = (unsigned)f2bf(pva[1].z, am) | ((unsigned)f2bf(pva[1].w, am) << 16);
            *(uint2*)&As[ra * LDK + ka]     = u0;
            *(uint2*)&As[ra * LDK + ka + 4] = u1;
            #pragma unroll
            for (int t = 0; t < 2; ++t) {
                uint2 ub;
                ub.x = (unsigned)f2bf(pvb[2*t].x, bm) | ((unsigned)f2bf(pvb[2*t].y, bm) << 16);
                ub.y = (unsigned)f2bf(pvb[2*t].z, bm) | ((unsigned)f2bf(pvb[2*t].w, bm) << 16);
                *(uint2*)&Bs[rb * LDK + kb + 8 * t] = ub;
                uint2 uc;
                uc.x = (unsigned)f2bf(pvb[2*t+1].x, bm) | ((unsigned)f2bf(pvb[2*t+1].y, bm) << 16);
                uc.y = (unsigned)f2bf(pvb[2*t+1].z, bm) | ((unsigned)f2bf(pvb[2*t+1].w, bm) << 16);
                *(uint2*)&Bs[rb * LDK + kb + 8 * t + 4] = uc;
            }
        }
        __syncthreads();

        if (ch + 1 < NCH) {
            const int gk = (ch + 1) * 32;
            const float4 z = {0.f, 0.f, 0.f, 0.f};
            const int gka = gk + ka;
            pva[0] = (gka + 4 <= HW) ? *(const float4*)(Abase + gka)     : z;
            pva[1] = (gka + 8 <= HW) ? *(const float4*)(Abase + gka + 4) : z;
            #pragma unroll
            for (int t = 0; t < 4; ++t) {
                const int gkb = gk + kb + 4 * t;
                pvb[t] = (gkb + 4 <= HW) ? *(const float4*)(Bbase + gkb) : z;
            }
        }

        bf16x8 av[2], bv[4];
        #pragma unroll
        for (int i = 0; i < 2; ++i)
            av[i] = *(const bf16x8*)&As[(mbase + i * 16 + ln15) * LDK + koff];
        #pragma unroll
        for (int j = 0; j < 4; ++j)
            bv[j] = *(const bf16x8*)&Bs[(nbase + j * 16 + ln15) * LDK + koff];
        #pragma unroll
        for (int i = 0; i < 2; ++i)
            #pragma unroll
            for (int j = 0; j < 4; ++j)
                acc[i][j] = __builtin_amdgcn_mfma_f32_16x16x32_bf16(
                    av[i], bv[j], acc[i][j], 0, 0, 0);
        __syncthreads();
    }

    // scatter: C/D layout col=lane&15, row=(lane>>4)*4+reg  [m89/m91]
    // unsafeAtomicAdd -> native ds_add_f32 (no CAS retry loop)
    int p2v[4];
    #pragma unroll
    for (int j = 0; j < 4; ++j)
        p2v[j] = h2t[nbase + j * 16 + ln15];

    #pragma unroll
    for (int i = 0; i < 2; ++i)
        #pragma unroll
        for (int qq = 0; qq < 4; ++qq) {
            const int p1 = h1t[mbase + i * 16 + qd * 4 + qq];
            #pragma unroll
            for (int j = 0; j < 4; ++j)
                unsafeAtomicAdd(&hist[(p1 + p2v[j]) & DMASK], acc[i][j][qq]);
        }

    __syncthreads();

    // flush: plain coalesced float4 stores to this block's partial slice
    float* Pslice = P + (size_t)(b * NSL + m) * D;
    #pragma unroll
    for (int i = 0; i < 8; ++i)
        ((float4*)Pslice)[tid + 256 * i] = ((const float4*)hist)[tid + 256 * i];
}

// ---------------------------------------------------------------------------
// Phase 3: out[b,d] = sum of 32 slices. 256 blocks x 256 threads.
// ---------------------------------------------------------------------------
__global__ __launch_bounds__(256) void reduce32(
    const float* __restrict__ P, float* __restrict__ out)
{
    const int idx4 = blockIdx.x * 256 + threadIdx.x;   // 0..65535
    const int b    = idx4 >> 11;
    const int d4   = idx4 & 2047;

    const float4* base = (const float4*)(P + (size_t)b * NSL * D) + d4;
    float4 acc = base[0];
    #pragma unroll
    for (int s = 1; s < NSL; ++s) {
        float4 v = base[s * (D / 4)];
        acc.x += v.x; acc.y += v.y; acc.z += v.z; acc.w += v.w;
    }
    ((float4*)out)[idx4] = acc;
}

// ---------------------------------------------------------------------------
extern "C" void kernel_launch(void* const* d_in, const int* in_sizes, int n_in,
                              void* d_out, int out_size, void* d_ws, size_t ws_size,
                              hipStream_t stream)
{
    const float* bottom1 = (const float*)d_in[0];
    const float* bottom2 = (const float*)d_in[1];
    const float* S1      = (const float*)d_in[2];
    const float* S2      = (const float*)d_in[3];
    float* out = (float*)d_out;

    float* P  = (float*)d_ws;                 // 1024 * 8192 floats = 32 MB
    int*   h1 = (int*)(P + (size_t)NB * NSL * D);
    int*   h2 = h1 + C;
    float* s1 = (float*)(h2 + C);
    float* s2 = s1 + C;

    extract2<<<1024, 256, 0, stream>>>(S1, S2, h1, s1, h2, s2);
    cbp_mfma<<<1024, 256, 0, stream>>>(bottom1, bottom2,
                                       h1, s1, h2, s2, P);
    reduce32<<<256, 256, 0, stream>>>(P, out);
}